// Round 10
// baseline (111.233 us; speedup 1.0000x reference)
//
#include <hip/hip_runtime.h>
#include <hip/hip_bf16.h>
#include <math.h>

#define HW 48
#define NPOS 2304      // 48*48
#define CCH 256
#define PCOLS 2500     // padded 50x50 grid per P row
#define PLANESZ (NPOS * CCH)   // elements per bf16 plane
#define KC 16
#define TM 128
#define TN 64

typedef __attribute__((ext_vector_type(8))) short short8v;
typedef __attribute__((ext_vector_type(16))) float f32x16;

// ---------------- phase: per-pixel sum of squares ---------------------------
__device__ inline void ph_ss2(int vb, const float* __restrict__ lr,
                              const float* __restrict__ ref, float* __restrict__ SS2,
                              float (*red)[64]) {
    const int img = vb / 36, bx = vb % 36;
    const float* imgp = img ? ref : lr;
    const int t = threadIdx.x;
    const int px = t & 63, cg = t >> 6;
    const int p = bx * 64 + px;
    const float* base = imgp + (size_t)cg * 64 * NPOS + p;
    float s = 0.f;
#pragma unroll 4
    for (int cc = 0; cc < 64; ++cc) {
        float v = base[(size_t)cc * NPOS];
        s = fmaf(v, v, s);
    }
    red[cg][px] = s;
    __syncthreads();
    if (cg == 0)
        SS2[img * NPOS + p] = red[0][px] + red[1][px] + red[2][px] + red[3][px];
}

// ---------------- phase: f32 -> 3-term bf16 split, fragment layout ----------
__device__ inline void ph_split(int local, const float* __restrict__ lr,
                                const float* __restrict__ ref, ushort* __restrict__ planes) {
    const int img = local / 288;
    const int gid = (local % 288) * 256 + threadIdx.x;   // octet id, 73728 per image
    const float* src = img ? ref : lr;
    const int lane = gid & 63;
    const int k16  = (gid >> 6) & 15;
    const int blk  = gid >> 10;
    const int pos  = blk * 32 + (lane & 31);
    const int c0   = k16 * 16 + (lane >> 5) * 8;
    ushort h8[8], m8[8], l8[8];
#pragma unroll
    for (int e = 0; e < 8; ++e) {
        float a = src[(size_t)(c0 + e) * NPOS + pos];
        __hip_bfloat16 hb = __float2bfloat16(a);
        float hf = __bfloat162float(hb);
        float r1 = a - hf;
        __hip_bfloat16 mb = __float2bfloat16(r1);
        float mf = __bfloat162float(mb);
        __hip_bfloat16 lb = __float2bfloat16(r1 - mf);
        h8[e] = *(ushort*)&hb;
        m8[e] = *(ushort*)&mb;
        l8[e] = *(ushort*)&lb;
    }
    ushort* ph = planes + (size_t)(img * 3 + 0) * PLANESZ + (size_t)gid * 8;
    ushort* pm = planes + (size_t)(img * 3 + 1) * PLANESZ + (size_t)gid * 8;
    ushort* pl = planes + (size_t)(img * 3 + 2) * PLANESZ + (size_t)gid * 8;
#pragma unroll
    for (int e = 0; e < 8; ++e) { ph[e] = h8[e]; pm[e] = m8[e]; pl[e] = l8[e]; }
}

// ---------------- phase: zero padded-border cells of P ----------------------
__device__ inline void ph_zero(int local, float* __restrict__ P) {
    const int idx = local * 256 + threadIdx.x;
    if (idx >= NPOS * 196) return;
    const int row = idx / 196, b = idx - row * 196;
    int pc;
    if (b < 50)       pc = b;
    else if (b < 100) pc = 2450 + (b - 50);
    else {
        const int i = b - 100;
        const int rr = 1 + (i >> 1);
        pc = rr * 50 + ((i & 1) ? 49 : 0);
    }
    P[(size_t)row * PCOLS + pc] = 0.f;
}

// ---------------- phase: NCHW -> NHWC transpose (1008 vblocks) --------------
// refs are read exactly once ever -> non-temporal loads keep L2 clean.
__device__ inline void ph_transpose(int b, const float* __restrict__ ref1,
                                    const float* __restrict__ ref2,
                                    const float* __restrict__ ref3,
                                    float* __restrict__ T3t, float* __restrict__ T2t,
                                    float* __restrict__ T1t, float (*tile)[65]) {
    const float* src; float* dst; int C, NPIX, tpx, tch;
    if (b < 144)      { src = ref3; dst = T3t; C = 256; NPIX = 2304;  tpx = b % 36;  tch = b / 36; }
    else if (b < 432) { const int lb = b - 144; src = ref2; dst = T2t; C = 128; NPIX = 9216;  tpx = lb % 144; tch = lb / 144; }
    else              { const int lb = b - 432; src = ref1; dst = T1t; C = 64;  NPIX = 36864; tpx = lb;       tch = 0; }
    const int t = threadIdx.x;
    const int px0 = tpx * 64, c0 = tch * 64;
#pragma unroll
    for (int r = 0; r < 16; ++r) {
        const int cl = r * 4 + (t >> 6), pl = t & 63;
        tile[cl][pl] = __builtin_nontemporal_load(&src[(size_t)(c0 + cl) * NPIX + px0 + pl]);
    }
    __syncthreads();
#pragma unroll
    for (int r = 0; r < 16; ++r) {
        const int pl = r * 4 + (t >> 6), cl = t & 63;
        dst[(size_t)(px0 + pl) * C + c0 + cl] = tile[cl][pl];
    }
}

// ---------------- K1: ss2 | split | zero-border | (transpose if bigws) ------
__global__ __launch_bounds__(256) void prep_kernel(const float* __restrict__ lr,
                                                   const float* __restrict__ ref,
                                                   const float* __restrict__ ref1,
                                                   const float* __restrict__ ref2,
                                                   const float* __restrict__ ref3,
                                                   float* __restrict__ SS2,
                                                   ushort* __restrict__ planes,
                                                   float* __restrict__ P,
                                                   float* __restrict__ T3t,
                                                   float* __restrict__ T2t,
                                                   float* __restrict__ T1t,
                                                   int do_split, int tbase) {
    __shared__ union {
        float red[4][64];
        float tile[64][65];
    } sm;
    const int b = blockIdx.x;
    if (b >= tbase) {
        ph_transpose(b - tbase, ref1, ref2, ref3, T3t, T2t, T1t, sm.tile);
        return;
    }
    if (do_split) {
        if (b < 72)        ph_ss2(b, lr, ref, SS2, sm.red);
        else if (b < 648)  ph_split(b - 72, lr, ref, planes);
        else               ph_zero(b - 648, P);
    } else {
        if (b < 72)        ph_ss2(b, lr, ref, SS2, sm.red);
        else               ph_zero(b - 72, P);
    }
}

// ---------------- standalone transpose (fallback path, aliases dead P) ------
__global__ __launch_bounds__(256) void transposeT_kernel(const float* __restrict__ ref1,
                                                         const float* __restrict__ ref2,
                                                         const float* __restrict__ ref3,
                                                         float* __restrict__ T3t,
                                                         float* __restrict__ T2t,
                                                         float* __restrict__ T1t) {
    __shared__ float tile[64][65];
    ph_transpose(blockIdx.x, ref1, ref2, ref3, T3t, T2t, T1t, tile);
}

// ---------------- phase: 3x3 stencil -> 1/max(norm,eps) ---------------------
__device__ inline void ph_invnorm(int vb, const float* __restrict__ SS2,
                                  float* __restrict__ inv2) {
    const int img = vb / 9;
    const int p = (vb % 9) * 256 + threadIdx.x;
    const float* SS = SS2 + img * NPOS;
    const int y = p / HW, x = p % HW;
    float s = 0.f;
#pragma unroll
    for (int di = -1; di <= 1; ++di) {
        int yy = y + di;
        if ((unsigned)yy >= HW) continue;
#pragma unroll
        for (int dj = -1; dj <= 1; ++dj) {
            int xx = x + dj;
            if ((unsigned)xx >= HW) continue;
            s += SS[yy * HW + xx];
        }
    }
    inv2[img * NPOS + p] = 1.f / fmaxf(sqrtf(s), 1e-12f);
}

// ---------------- phase: MFMA correlation GEMM (3-term split) ---------------
__device__ inline void ph_gemm(int g, const ushort* __restrict__ planes,
                               float* __restrict__ P) {
    const int bxg = g % 72, byg = g / 72;
    const int t = threadIdx.x, lane = t & 63, w = t >> 6;
    const int nblk0 = bxg;
    const int ablk  = byg * 4 + w;

    const ushort* baseA  = planes + ((size_t)(ablk * 16) * 64 + lane) * 8;
    const ushort* baseB0 = planes + (size_t)3 * PLANESZ + ((size_t)(nblk0 * 16) * 64 + lane) * 8;

    f32x16 acc0 = {};
#pragma unroll 4
    for (int k = 0; k < 16; ++k) {
        const int fo = k * 512;
        short8v ah = *(const short8v*)(baseA + fo);
        short8v am = *(const short8v*)(baseA + PLANESZ + fo);
        short8v al = *(const short8v*)(baseA + 2 * PLANESZ + fo);
        short8v bh0 = *(const short8v*)(baseB0 + fo);
        short8v bm0 = *(const short8v*)(baseB0 + PLANESZ + fo);
        short8v bl0 = *(const short8v*)(baseB0 + 2 * PLANESZ + fo);
        acc0 = __builtin_amdgcn_mfma_f32_32x32x16_bf16(ah, bh0, acc0, 0, 0, 0);
        acc0 = __builtin_amdgcn_mfma_f32_32x32x16_bf16(ah, bm0, acc0, 0, 0, 0);
        acc0 = __builtin_amdgcn_mfma_f32_32x32x16_bf16(am, bh0, acc0, 0, 0, 0);
        acc0 = __builtin_amdgcn_mfma_f32_32x32x16_bf16(ah, bl0, acc0, 0, 0, 0);
        acc0 = __builtin_amdgcn_mfma_f32_32x32x16_bf16(al, bh0, acc0, 0, 0, 0);
        acc0 = __builtin_amdgcn_mfma_f32_32x32x16_bf16(am, bm0, acc0, 0, 0, 0);
    }
    const int m0 = byg * 128 + w * 32;
    const int half = lane >> 5;
    const int colA = nblk0 * 32 + (lane & 31);
    const int pcA = (colA / 48) * 50 + colA % 48 + 51;
#pragma unroll
    for (int r = 0; r < 16; ++r) {
        const int row = (r & 3) + 8 * (r >> 2) + 4 * half;
        P[(size_t)(m0 + row) * PCOLS + pcA] = acc0[r];
    }
}

// ---------------- K2: invnorm (18 blocks) | gemm (1296 blocks) --------------
__global__ __launch_bounds__(256) void corr_kernel(const float* __restrict__ SS2,
                                                   float* __restrict__ inv2,
                                                   const ushort* __restrict__ planes,
                                                   float* __restrict__ P,
                                                   int do_gemm) {
    const int b = blockIdx.x;
    if (b < 18)          ph_invnorm(b, SS2, inv2);
    else if (do_gemm)    ph_gemm(b - 18, planes, P);
}

// ---------------- f32 fallback GEMM (if workspace too small) ----------------
__global__ __launch_bounds__(256) void gemm_p_kernel(const float* __restrict__ lr,
                                                     const float* __restrict__ ref,
                                                     float* __restrict__ P) {
    __shared__ float As[KC][TM];
    __shared__ float Bs[KC][TN];
    const int t  = threadIdx.x;
    const int tx = t & 15, ty = t >> 4;
    const int lp0 = blockIdx.y * TM, rp0 = blockIdx.x * TN;
    const int ac0 = t >> 5,        acol0 = (t & 31) << 2;
    const int ac1 = (t + 256) >> 5, acol1 = acol0;
    const int bc = t >> 4, bcol = (t & 15) << 2;
    float acc[8][4] = {};
    for (int c0 = 0; c0 < CCH; c0 += KC) {
        float4 a0 = *(const float4*)(lr  + (size_t)(c0 + ac0) * NPOS + lp0 + acol0);
        float4 a1 = *(const float4*)(lr  + (size_t)(c0 + ac1) * NPOS + lp0 + acol1);
        float4 b0 = *(const float4*)(ref + (size_t)(c0 + bc)  * NPOS + rp0 + bcol);
        __syncthreads();
        *(float4*)&As[ac0][acol0] = a0;
        *(float4*)&As[ac1][acol1] = a1;
        *(float4*)&Bs[bc][bcol]   = b0;
        __syncthreads();
#pragma unroll
        for (int kk = 0; kk < KC; ++kk) {
            float4 aA = *(const float4*)&As[kk][ty * 8];
            float4 aB = *(const float4*)&As[kk][ty * 8 + 4];
            float4 bb = *(const float4*)&Bs[kk][tx * 4];
            const float av[8] = {aA.x, aA.y, aA.z, aA.w, aB.x, aB.y, aB.z, aB.w};
            const float bv[4] = {bb.x, bb.y, bb.z, bb.w};
#pragma unroll
            for (int i = 0; i < 8; ++i)
#pragma unroll
                for (int j = 0; j < 4; ++j)
                    acc[i][j] = fmaf(av[i], bv[j], acc[i][j]);
        }
    }
    const int col0 = rp0 + tx * 4;
    const int pc0  = (col0 / 48) * 50 + (col0 % 48) + 51;
#pragma unroll
    for (int i = 0; i < 8; ++i) {
        const int m = lp0 + ty * 8 + i;
        float4 v = make_float4(acc[i][0], acc[i][1], acc[i][2], acc[i][3]);
        __builtin_memcpy(P + (size_t)m * PCOLS + pc0, &v, 16);
    }
}

// ---------------- K3: paired R-reconstruction + max/argmax ------------------
// Block handles (l0, l0+1). 12 physical P rows; the 6 shared rows are served
// by one float4 + one scalar (25% fewer bytes). Accumulation order per l is
// bitwise-identical to the unpaired version (di,dj ascending).
__global__ __launch_bounds__(192) void maxarg_kernel(const float* __restrict__ P,
                                                     const float* __restrict__ inr,
                                                     const float* __restrict__ inl,
                                                     float* __restrict__ S,
                                                     int* __restrict__ arg) {
    const int bid = blockIdx.x;
    const int pl  = (bid & 7) * 144 + (bid >> 3);   // bijective, 1152 = 8*144
    const int yl  = pl / 24, xl0 = (pl % 24) * 2;
    const int l0  = yl * HW + xl0;
    const int t   = threadIdx.x;

    bool vrow[3][4];
    const float* rp[3][4];
#pragma unroll
    for (int di = -1; di <= 1; ++di)
#pragma unroll
        for (int j = -1; j <= 2; ++j) {
            vrow[di + 1][j + 1] = ((unsigned)(yl + di) < HW) && ((unsigned)(xl0 + j) < HW);
            rp[di + 1][j + 1]   = P + (ptrdiff_t)(l0 + di * HW + j) * PCOLS + (di * 50 + j);
        }

    float best0 = -1e30f, best1 = -1e30f;
    int bestr0 = 0, bestr1 = 0;
#pragma unroll
    for (int vv = 0; vv < 3; ++vv) {
        const int v   = t + vv * 192;          // vec id 0..575
        const int yr  = v / 12;
        const int xr4 = (v - yr * 12) << 2;
        const int q0  = yr * 50 + xr4 + 51;
        const int r0  = yr * HW + xr4;
        float4 a0 = make_float4(0.f, 0.f, 0.f, 0.f);
        float4 a1 = make_float4(0.f, 0.f, 0.f, 0.f);
#pragma unroll
        for (int di = 0; di < 3; ++di) {
            // j = -1: l0 term dj=-1
            if (vrow[di][0]) {
                float4 x;
                __builtin_memcpy(&x, rp[di][0] + q0, 16);
                a0.x += x.x; a0.y += x.y; a0.z += x.z; a0.w += x.w;
            }
            // j = 0,1: shared rows (l0 dj=j, l1 dj=j-1)
#pragma unroll
            for (int j = 1; j <= 2; ++j) {
                if (vrow[di][j]) {
                    float4 x;
                    __builtin_memcpy(&x, rp[di][j] + q0 - 1, 16);
                    const float s = *(rp[di][j] + q0 + 3);
                    a1.x += x.x; a1.y += x.y; a1.z += x.z; a1.w += x.w;
                    a0.x += x.y; a0.y += x.z; a0.z += x.w; a0.w += s;
                }
            }
            // j = 2: l1 term dj=1
            if (vrow[di][3]) {
                float4 x;
                __builtin_memcpy(&x, rp[di][3] + q0 - 1, 16);
                a1.x += x.x; a1.y += x.y; a1.z += x.z; a1.w += x.w;
            }
        }
        const float4 w = *(const float4*)(inr + r0);
        const float v0[4] = {a0.x * w.x, a0.y * w.y, a0.z * w.z, a0.w * w.w};
        const float v1[4] = {a1.x * w.x, a1.y * w.y, a1.z * w.z, a1.w * w.w};
#pragma unroll
        for (int k = 0; k < 4; ++k) {
            if (v0[k] > best0) { best0 = v0[k]; bestr0 = r0 + k; }
            if (v1[k] > best1) { best1 = v1[k]; bestr1 = r0 + k; }
        }
    }

    __shared__ float bv0[256], bv1[256];
    __shared__ int   br0[256], br1[256];
    bv0[t] = best0; br0[t] = bestr0;
    bv1[t] = best1; br1[t] = bestr1;
    if (t < 64) {
        bv0[192 + t] = -1e30f; br0[192 + t] = 0;
        bv1[192 + t] = -1e30f; br1[192 + t] = 0;
    }
    __syncthreads();
    for (int s2 = 128; s2 > 0; s2 >>= 1) {
        if (t < s2) {
            float x0 = bv0[t + s2]; int y0 = br0[t + s2];
            if (x0 > bv0[t] || (x0 == bv0[t] && y0 < br0[t])) { bv0[t] = x0; br0[t] = y0; }
            float x1 = bv1[t + s2]; int y1 = br1[t + s2];
            if (x1 > bv1[t] || (x1 == bv1[t] && y1 < br1[t])) { bv1[t] = x1; br1[t] = y1; }
        }
        __syncthreads();
    }
    if (t == 0) {
        S[l0]     = bv0[0] * inl[l0];
        arg[l0]   = br0[0];
        S[l0 + 1] = bv1[0] * inl[l0 + 1];
        arg[l0 + 1] = br1[0];
    }
}

// ---------------- K4: fold from NHWC refs, coalesced 1KB gathers ------------
// Outputs are never re-read -> non-temporal stores keep L2 for the NHWC refs.
template <int S_, int C, int H>
__device__ inline void foldT(const float* __restrict__ refT, const int* __restrict__ arg,
                             float* __restrict__ out, int u, int lane) {
    const int y = u / 48, m = u % 48;
    const int ty_ = y / S_ + 1;            // (y+PAD)/S_, PAD==S_
    float4 acc = make_float4(0.f, 0.f, 0.f, 0.f);
#pragma unroll
    for (int a = 0; a < 3; ++a) {
        const int oy = ty_ - a;
        if ((unsigned)oy >= HW) continue;
        const int di = y + S_ - S_ * oy;   // in [0, 3S)
#pragma unroll
        for (int b = 0; b < 3; ++b) {
            const int ox = m + 1 - b;
            if ((unsigned)ox >= HW) continue;
            const int ar = arg[oy * HW + ox];
            const int ry = ar / HW, rx = ar % HW;
            const int yy  = S_ * ry + di - S_;
            const int xx0 = S_ * (rx + b - 1);
            if ((unsigned)yy < H && (unsigned)xx0 < H) {
                float4 v;
                __builtin_memcpy(&v, refT + ((size_t)yy * H + xx0) * C + lane * 4, 16);
                acc.x += v.x; acc.y += v.y; acc.z += v.z; acc.w += v.w;
            }
        }
    }
    const int idx = lane * 4;
    const int xx = idx / C;                // pixel within quad
    const int c  = idx % C;                // 4 consecutive channels
    const int x  = m * S_ + xx;
    const float vals[4] = {acc.x, acc.y, acc.z, acc.w};
    float* op = out + (size_t)c * (H * H) + (size_t)y * H + x;
#pragma unroll
    for (int e = 0; e < 4; ++e)
        __builtin_nontemporal_store(vals[e] * (1.f / 9.f), &op[(size_t)e * (H * H)]);
}

__global__ __launch_bounds__(256) void foldT_kernel(const float* __restrict__ T1t,
                                                    const float* __restrict__ T2t,
                                                    const float* __restrict__ T3t,
                                                    const int* __restrict__ argb,
                                                    float* __restrict__ T1,
                                                    float* __restrict__ T2,
                                                    float* __restrict__ T3) {
    const int b = blockIdx.x, w = threadIdx.x >> 6, lane = threadIdx.x & 63;
    if (b < 576)        foldT<1, 256, 48>(T3t, argb, T3, b * 4 + w, lane);
    else if (b < 1728)  foldT<2, 128, 96>(T2t, argb, T2, (b - 576) * 4 + w, lane);
    else                foldT<4, 64, 192>(T1t, argb, T1, (b - 1728) * 4 + w, lane);
}

extern "C" void kernel_launch(void* const* d_in, const int* in_sizes, int n_in,
                              void* d_out, int out_size, void* d_ws, size_t ws_size,
                              hipStream_t stream) {
    const float* lrsr  = (const float*)d_in[0];  // (1,256,48,48)
    const float* refsr = (const float*)d_in[1];  // (1,256,48,48)
    const float* ref1  = (const float*)d_in[2];  // (1,64,192,192)
    const float* ref2  = (const float*)d_in[3];  // (1,128,96,96)
    const float* ref3  = (const float*)d_in[4];  // (1,256,48,48)

    float* out = (float*)d_out;
    float* S   = out;                         // 2304
    float* T3  = S  + NPOS;                   // 256*48*48
    float* T2  = T3 + 256 * 48 * 48;          // 128*96*96
    float* T1  = T2 + 128 * 96 * 96;          // 64*192*192

    float*  P      = (float*)d_ws;                    // 2304*2500 f32 = 23.04 MB
    float*  SS2    = P + (size_t)NPOS * PCOLS;        // 2*2304
    float*  inv2   = SS2 + 2 * NPOS;                  // 2*2304 (inl, inr)
    int*    argb   = (int*)(inv2 + 2 * NPOS);         // 2304
    ushort* planes = (ushort*)(argb + NPOS);          // 6*PLANESZ bf16 = 7.08 MB
    float*  inl    = inv2;
    float*  inr    = inv2 + NPOS;

    const size_t need  = ((size_t)NPOS * PCOLS + 5 * NPOS) * 4 + (size_t)6 * PLANESZ * 2;
    const size_t nhwcB = (size_t)(2304 * 256 + 9216 * 128 + 36864 * 64) * 4;  // 16.5 MB
    const int mfma_path = ws_size >= need ? 1 : 0;
    const int bigws     = ws_size >= need + nhwcB ? 1 : 0;

    // NHWC refs: separate region if it fits, else alias dead-after-maxarg P
    float* T3t = bigws ? (float*)((char*)d_ws + need) : P;
    float* T2t = T3t + 2304 * 256;
    float* T1t = T2t + 9216 * 128;

    // K1: ss2 + split + P border zeroing (+ transpose when bigws)
    {
        const int tbase = mfma_path ? 2412 : 1836;
        const int grid  = tbase + (bigws ? 1008 : 0);
        prep_kernel<<<grid, 256, 0, stream>>>(lrsr, refsr, ref1, ref2, ref3,
                                              SS2, planes, P, T3t, T2t, T1t,
                                              mfma_path, bigws ? tbase : grid + 1);
    }

    // K2: invnorm + gemm
    if (mfma_path) {
        corr_kernel<<<18 + 1296, 256, 0, stream>>>(SS2, inv2, planes, P, 1);
    } else {
        corr_kernel<<<18, 256, 0, stream>>>(SS2, inv2, planes, P, 0);
        gemm_p_kernel<<<dim3(NPOS / TN, NPOS / TM), 256, 0, stream>>>(lrsr, refsr, P);
    }

    // K3: paired maxarg (last reader of P)
    maxarg_kernel<<<1152, 192, 0, stream>>>(P, inr, inl, S, argb);

    // fallback path: transpose into dead P region after maxarg
    if (!bigws)
        transposeT_kernel<<<1008, 256, 0, stream>>>(ref1, ref2, ref3, T3t, T2t, T1t);

    // K4: coalesced folds with NT stores
    foldT_kernel<<<4032, 256, 0, stream>>>(T1t, T2t, T3t, argb, T1, T2, T3);
}

// Round 11
// 85.895 us; speedup vs baseline: 1.2950x; 1.2950x over previous
//
#include <hip/hip_runtime.h>
#include <hip/hip_bf16.h>
#include <math.h>

#define HW 48
#define NPOS 2304      // 48*48
#define CCH 256
#define PCOLS 2500     // padded 50x50 grid per P row
#define PLANESZ (NPOS * CCH)   // elements per bf16 plane
#define KC 16
#define TM 128
#define TN 64

typedef __attribute__((ext_vector_type(8))) short short8v;
typedef __attribute__((ext_vector_type(16))) float f32x16;

// ---------------- phase: per-pixel sum of squares ---------------------------
__device__ inline void ph_ss2(int vb, const float* __restrict__ lr,
                              const float* __restrict__ ref, float* __restrict__ SS2,
                              float (*red)[64]) {
    const int img = vb / 36, bx = vb % 36;
    const float* imgp = img ? ref : lr;
    const int t = threadIdx.x;
    const int px = t & 63, cg = t >> 6;
    const int p = bx * 64 + px;
    const float* base = imgp + (size_t)cg * 64 * NPOS + p;
    float s = 0.f;
#pragma unroll 4
    for (int cc = 0; cc < 64; ++cc) {
        float v = base[(size_t)cc * NPOS];
        s = fmaf(v, v, s);
    }
    red[cg][px] = s;
    __syncthreads();
    if (cg == 0)
        SS2[img * NPOS + p] = red[0][px] + red[1][px] + red[2][px] + red[3][px];
}

// ---------------- phase: f32 -> 3-term bf16 split, fragment layout ----------
__device__ inline void ph_split(int local, const float* __restrict__ lr,
                                const float* __restrict__ ref, ushort* __restrict__ planes) {
    const int img = local / 288;
    const int gid = (local % 288) * 256 + threadIdx.x;   // octet id, 73728 per image
    const float* src = img ? ref : lr;
    const int lane = gid & 63;
    const int k16  = (gid >> 6) & 15;
    const int blk  = gid >> 10;
    const int pos  = blk * 32 + (lane & 31);
    const int c0   = k16 * 16 + (lane >> 5) * 8;
    ushort h8[8], m8[8], l8[8];
#pragma unroll
    for (int e = 0; e < 8; ++e) {
        float a = src[(size_t)(c0 + e) * NPOS + pos];
        __hip_bfloat16 hb = __float2bfloat16(a);
        float hf = __bfloat162float(hb);
        float r1 = a - hf;
        __hip_bfloat16 mb = __float2bfloat16(r1);
        float mf = __bfloat162float(mb);
        __hip_bfloat16 lb = __float2bfloat16(r1 - mf);
        h8[e] = *(ushort*)&hb;
        m8[e] = *(ushort*)&mb;
        l8[e] = *(ushort*)&lb;
    }
    ushort* ph = planes + (size_t)(img * 3 + 0) * PLANESZ + (size_t)gid * 8;
    ushort* pm = planes + (size_t)(img * 3 + 1) * PLANESZ + (size_t)gid * 8;
    ushort* pl = planes + (size_t)(img * 3 + 2) * PLANESZ + (size_t)gid * 8;
#pragma unroll
    for (int e = 0; e < 8; ++e) { ph[e] = h8[e]; pm[e] = m8[e]; pl[e] = l8[e]; }
}

// ---------------- phase: zero padded-border cells of P ----------------------
__device__ inline void ph_zero(int local, float* __restrict__ P) {
    const int idx = local * 256 + threadIdx.x;
    if (idx >= NPOS * 196) return;
    const int row = idx / 196, b = idx - row * 196;
    int pc;
    if (b < 50)       pc = b;
    else if (b < 100) pc = 2450 + (b - 50);
    else {
        const int i = b - 100;
        const int rr = 1 + (i >> 1);
        pc = rr * 50 + ((i & 1) ? 49 : 0);
    }
    P[(size_t)row * PCOLS + pc] = 0.f;
}

// ---------------- phase: NCHW -> NHWC transpose (1008 vblocks) --------------
// refs are read exactly once ever -> non-temporal loads keep L2 clean.
__device__ inline void ph_transpose(int b, const float* __restrict__ ref1,
                                    const float* __restrict__ ref2,
                                    const float* __restrict__ ref3,
                                    float* __restrict__ T3t, float* __restrict__ T2t,
                                    float* __restrict__ T1t, float (*tile)[65]) {
    const float* src; float* dst; int C, NPIX, tpx, tch;
    if (b < 144)      { src = ref3; dst = T3t; C = 256; NPIX = 2304;  tpx = b % 36;  tch = b / 36; }
    else if (b < 432) { const int lb = b - 144; src = ref2; dst = T2t; C = 128; NPIX = 9216;  tpx = lb % 144; tch = lb / 144; }
    else              { const int lb = b - 432; src = ref1; dst = T1t; C = 64;  NPIX = 36864; tpx = lb;       tch = 0; }
    const int t = threadIdx.x;
    const int px0 = tpx * 64, c0 = tch * 64;
#pragma unroll
    for (int r = 0; r < 16; ++r) {
        const int cl = r * 4 + (t >> 6), pl = t & 63;
        tile[cl][pl] = __builtin_nontemporal_load(&src[(size_t)(c0 + cl) * NPIX + px0 + pl]);
    }
    __syncthreads();
#pragma unroll
    for (int r = 0; r < 16; ++r) {
        const int pl = r * 4 + (t >> 6), cl = t & 63;
        dst[(size_t)(px0 + pl) * C + c0 + cl] = tile[cl][pl];
    }
}

// ---------------- K1: ss2 | split | zero-border | (transpose if bigws) ------
__global__ __launch_bounds__(256) void prep_kernel(const float* __restrict__ lr,
                                                   const float* __restrict__ ref,
                                                   const float* __restrict__ ref1,
                                                   const float* __restrict__ ref2,
                                                   const float* __restrict__ ref3,
                                                   float* __restrict__ SS2,
                                                   ushort* __restrict__ planes,
                                                   float* __restrict__ P,
                                                   float* __restrict__ T3t,
                                                   float* __restrict__ T2t,
                                                   float* __restrict__ T1t,
                                                   int do_split, int tbase) {
    __shared__ union {
        float red[4][64];
        float tile[64][65];
    } sm;
    const int b = blockIdx.x;
    if (b >= tbase) {
        ph_transpose(b - tbase, ref1, ref2, ref3, T3t, T2t, T1t, sm.tile);
        return;
    }
    if (do_split) {
        if (b < 72)        ph_ss2(b, lr, ref, SS2, sm.red);
        else if (b < 648)  ph_split(b - 72, lr, ref, planes);
        else               ph_zero(b - 648, P);
    } else {
        if (b < 72)        ph_ss2(b, lr, ref, SS2, sm.red);
        else               ph_zero(b - 72, P);
    }
}

// ---------------- standalone transpose (fallback path, aliases dead P) ------
__global__ __launch_bounds__(256) void transposeT_kernel(const float* __restrict__ ref1,
                                                         const float* __restrict__ ref2,
                                                         const float* __restrict__ ref3,
                                                         float* __restrict__ T3t,
                                                         float* __restrict__ T2t,
                                                         float* __restrict__ T1t) {
    __shared__ float tile[64][65];
    ph_transpose(blockIdx.x, ref1, ref2, ref3, T3t, T2t, T1t, tile);
}

// ---------------- phase: 3x3 stencil -> 1/max(norm,eps) ---------------------
__device__ inline void ph_invnorm(int vb, const float* __restrict__ SS2,
                                  float* __restrict__ inv2) {
    const int img = vb / 9;
    const int p = (vb % 9) * 256 + threadIdx.x;
    const float* SS = SS2 + img * NPOS;
    const int y = p / HW, x = p % HW;
    float s = 0.f;
#pragma unroll
    for (int di = -1; di <= 1; ++di) {
        int yy = y + di;
        if ((unsigned)yy >= HW) continue;
#pragma unroll
        for (int dj = -1; dj <= 1; ++dj) {
            int xx = x + dj;
            if ((unsigned)xx >= HW) continue;
            s += SS[yy * HW + xx];
        }
    }
    inv2[img * NPOS + p] = 1.f / fmaxf(sqrtf(s), 1e-12f);
}

// ---------------- phase: MFMA correlation GEMM (3-term split) ---------------
__device__ inline void ph_gemm(int g, const ushort* __restrict__ planes,
                               float* __restrict__ P) {
    const int bxg = g % 72, byg = g / 72;
    const int t = threadIdx.x, lane = t & 63, w = t >> 6;
    const int nblk0 = bxg;
    const int ablk  = byg * 4 + w;

    const ushort* baseA  = planes + ((size_t)(ablk * 16) * 64 + lane) * 8;
    const ushort* baseB0 = planes + (size_t)3 * PLANESZ + ((size_t)(nblk0 * 16) * 64 + lane) * 8;

    f32x16 acc0 = {};
#pragma unroll 4
    for (int k = 0; k < 16; ++k) {
        const int fo = k * 512;
        short8v ah = *(const short8v*)(baseA + fo);
        short8v am = *(const short8v*)(baseA + PLANESZ + fo);
        short8v al = *(const short8v*)(baseA + 2 * PLANESZ + fo);
        short8v bh0 = *(const short8v*)(baseB0 + fo);
        short8v bm0 = *(const short8v*)(baseB0 + PLANESZ + fo);
        short8v bl0 = *(const short8v*)(baseB0 + 2 * PLANESZ + fo);
        acc0 = __builtin_amdgcn_mfma_f32_32x32x16_bf16(ah, bh0, acc0, 0, 0, 0);
        acc0 = __builtin_amdgcn_mfma_f32_32x32x16_bf16(ah, bm0, acc0, 0, 0, 0);
        acc0 = __builtin_amdgcn_mfma_f32_32x32x16_bf16(am, bh0, acc0, 0, 0, 0);
        acc0 = __builtin_amdgcn_mfma_f32_32x32x16_bf16(ah, bl0, acc0, 0, 0, 0);
        acc0 = __builtin_amdgcn_mfma_f32_32x32x16_bf16(al, bh0, acc0, 0, 0, 0);
        acc0 = __builtin_amdgcn_mfma_f32_32x32x16_bf16(am, bm0, acc0, 0, 0, 0);
    }
    const int m0 = byg * 128 + w * 32;
    const int half = lane >> 5;
    const int colA = nblk0 * 32 + (lane & 31);
    const int pcA = (colA / 48) * 50 + colA % 48 + 51;
#pragma unroll
    for (int r = 0; r < 16; ++r) {
        const int row = (r & 3) + 8 * (r >> 2) + 4 * half;
        P[(size_t)(m0 + row) * PCOLS + pcA] = acc0[r];
    }
}

// ---------------- K2: invnorm (18 blocks) | gemm (1296 blocks) --------------
__global__ __launch_bounds__(256) void corr_kernel(const float* __restrict__ SS2,
                                                   float* __restrict__ inv2,
                                                   const ushort* __restrict__ planes,
                                                   float* __restrict__ P,
                                                   int do_gemm) {
    const int b = blockIdx.x;
    if (b < 18)          ph_invnorm(b, SS2, inv2);
    else if (do_gemm)    ph_gemm(b - 18, planes, P);
}

// ---------------- f32 fallback GEMM (if workspace too small) ----------------
__global__ __launch_bounds__(256) void gemm_p_kernel(const float* __restrict__ lr,
                                                     const float* __restrict__ ref,
                                                     float* __restrict__ P) {
    __shared__ float As[KC][TM];
    __shared__ float Bs[KC][TN];
    const int t  = threadIdx.x;
    const int tx = t & 15, ty = t >> 4;
    const int lp0 = blockIdx.y * TM, rp0 = blockIdx.x * TN;
    const int ac0 = t >> 5,        acol0 = (t & 31) << 2;
    const int ac1 = (t + 256) >> 5, acol1 = acol0;
    const int bc = t >> 4, bcol = (t & 15) << 2;
    float acc[8][4] = {};
    for (int c0 = 0; c0 < CCH; c0 += KC) {
        float4 a0 = *(const float4*)(lr  + (size_t)(c0 + ac0) * NPOS + lp0 + acol0);
        float4 a1 = *(const float4*)(lr  + (size_t)(c0 + ac1) * NPOS + lp0 + acol1);
        float4 b0 = *(const float4*)(ref + (size_t)(c0 + bc)  * NPOS + rp0 + bcol);
        __syncthreads();
        *(float4*)&As[ac0][acol0] = a0;
        *(float4*)&As[ac1][acol1] = a1;
        *(float4*)&Bs[bc][bcol]   = b0;
        __syncthreads();
#pragma unroll
        for (int kk = 0; kk < KC; ++kk) {
            float4 aA = *(const float4*)&As[kk][ty * 8];
            float4 aB = *(const float4*)&As[kk][ty * 8 + 4];
            float4 bb = *(const float4*)&Bs[kk][tx * 4];
            const float av[8] = {aA.x, aA.y, aA.z, aA.w, aB.x, aB.y, aB.z, aB.w};
            const float bv[4] = {bb.x, bb.y, bb.z, bb.w};
#pragma unroll
            for (int i = 0; i < 8; ++i)
#pragma unroll
                for (int j = 0; j < 4; ++j)
                    acc[i][j] = fmaf(av[i], bv[j], acc[i][j]);
        }
    }
    const int col0 = rp0 + tx * 4;
    const int pc0  = (col0 / 48) * 50 + (col0 % 48) + 51;
#pragma unroll
    for (int i = 0; i < 8; ++i) {
        const int m = lp0 + ty * 8 + i;
        float4 v = make_float4(acc[i][0], acc[i][1], acc[i][2], acc[i][3]);
        __builtin_memcpy(P + (size_t)m * PCOLS + pc0, &v, 16);
    }
}

// ---------------- K3: paired R-reconstruction + max/argmax ------------------
// Block handles (l0, l0+1). 12 physical P rows; the 6 shared rows are served
// by one float4 + one scalar (25% fewer bytes). Accumulation order per l is
// bitwise-identical to the unpaired version (di,dj ascending).
__global__ __launch_bounds__(192) void maxarg_kernel(const float* __restrict__ P,
                                                     const float* __restrict__ inr,
                                                     const float* __restrict__ inl,
                                                     float* __restrict__ S,
                                                     int* __restrict__ arg) {
    const int bid = blockIdx.x;
    const int pl  = (bid & 7) * 144 + (bid >> 3);   // bijective, 1152 = 8*144
    const int yl  = pl / 24, xl0 = (pl % 24) * 2;
    const int l0  = yl * HW + xl0;
    const int t   = threadIdx.x;

    bool vrow[3][4];
    const float* rp[3][4];
#pragma unroll
    for (int di = -1; di <= 1; ++di)
#pragma unroll
        for (int j = -1; j <= 2; ++j) {
            vrow[di + 1][j + 1] = ((unsigned)(yl + di) < HW) && ((unsigned)(xl0 + j) < HW);
            rp[di + 1][j + 1]   = P + (ptrdiff_t)(l0 + di * HW + j) * PCOLS + (di * 50 + j);
        }

    float best0 = -1e30f, best1 = -1e30f;
    int bestr0 = 0, bestr1 = 0;
#pragma unroll
    for (int vv = 0; vv < 3; ++vv) {
        const int v   = t + vv * 192;          // vec id 0..575
        const int yr  = v / 12;
        const int xr4 = (v - yr * 12) << 2;
        const int q0  = yr * 50 + xr4 + 51;
        const int r0  = yr * HW + xr4;
        float4 a0 = make_float4(0.f, 0.f, 0.f, 0.f);
        float4 a1 = make_float4(0.f, 0.f, 0.f, 0.f);
#pragma unroll
        for (int di = 0; di < 3; ++di) {
            if (vrow[di][0]) {
                float4 x;
                __builtin_memcpy(&x, rp[di][0] + q0, 16);
                a0.x += x.x; a0.y += x.y; a0.z += x.z; a0.w += x.w;
            }
#pragma unroll
            for (int j = 1; j <= 2; ++j) {
                if (vrow[di][j]) {
                    float4 x;
                    __builtin_memcpy(&x, rp[di][j] + q0 - 1, 16);
                    const float s = *(rp[di][j] + q0 + 3);
                    a1.x += x.x; a1.y += x.y; a1.z += x.z; a1.w += x.w;
                    a0.x += x.y; a0.y += x.z; a0.z += x.w; a0.w += s;
                }
            }
            if (vrow[di][3]) {
                float4 x;
                __builtin_memcpy(&x, rp[di][3] + q0 - 1, 16);
                a1.x += x.x; a1.y += x.y; a1.z += x.z; a1.w += x.w;
            }
        }
        const float4 w = *(const float4*)(inr + r0);
        const float v0[4] = {a0.x * w.x, a0.y * w.y, a0.z * w.z, a0.w * w.w};
        const float v1[4] = {a1.x * w.x, a1.y * w.y, a1.z * w.z, a1.w * w.w};
#pragma unroll
        for (int k = 0; k < 4; ++k) {
            if (v0[k] > best0) { best0 = v0[k]; bestr0 = r0 + k; }
            if (v1[k] > best1) { best1 = v1[k]; bestr1 = r0 + k; }
        }
    }

    __shared__ float bv0[256], bv1[256];
    __shared__ int   br0[256], br1[256];
    bv0[t] = best0; br0[t] = bestr0;
    bv1[t] = best1; br1[t] = bestr1;
    if (t < 64) {
        bv0[192 + t] = -1e30f; br0[192 + t] = 0;
        bv1[192 + t] = -1e30f; br1[192 + t] = 0;
    }
    __syncthreads();
    for (int s2 = 128; s2 > 0; s2 >>= 1) {
        if (t < s2) {
            float x0 = bv0[t + s2]; int y0 = br0[t + s2];
            if (x0 > bv0[t] || (x0 == bv0[t] && y0 < br0[t])) { bv0[t] = x0; br0[t] = y0; }
            float x1 = bv1[t + s2]; int y1 = br1[t + s2];
            if (x1 > bv1[t] || (x1 == bv1[t] && y1 < br1[t])) { bv1[t] = x1; br1[t] = y1; }
        }
        __syncthreads();
    }
    if (t == 0) {
        S[l0]     = bv0[0] * inl[l0];
        arg[l0]   = br0[0];
        S[l0 + 1] = bv1[0] * inl[l0 + 1];
        arg[l0 + 1] = br1[0];
    }
}

// ---------------- K4: fold from NHWC refs, coalesced 1KB gathers ------------
// Stores: plain per-lane dword scatter -- write-back L2 coalesces them
// (round-10 lesson: NT stores on scattered dwords = 3.6x HBM write
// amplification, 54.7us vs ~25us; round-8: LDS staging also a net loss).
template <int S_, int C, int H>
__device__ inline void foldT(const float* __restrict__ refT, const int* __restrict__ arg,
                             float* __restrict__ out, int u, int lane) {
    const int y = u / 48, m = u % 48;
    const int ty_ = y / S_ + 1;            // (y+PAD)/S_, PAD==S_
    float4 acc = make_float4(0.f, 0.f, 0.f, 0.f);
#pragma unroll
    for (int a = 0; a < 3; ++a) {
        const int oy = ty_ - a;
        if ((unsigned)oy >= HW) continue;
        const int di = y + S_ - S_ * oy;   // in [0, 3S)
#pragma unroll
        for (int b = 0; b < 3; ++b) {
            const int ox = m + 1 - b;
            if ((unsigned)ox >= HW) continue;
            const int ar = arg[oy * HW + ox];
            const int ry = ar / HW, rx = ar % HW;
            const int yy  = S_ * ry + di - S_;
            const int xx0 = S_ * (rx + b - 1);
            if ((unsigned)yy < H && (unsigned)xx0 < H) {
                float4 v;
                __builtin_memcpy(&v, refT + ((size_t)yy * H + xx0) * C + lane * 4, 16);
                acc.x += v.x; acc.y += v.y; acc.z += v.z; acc.w += v.w;
            }
        }
    }
    const int idx = lane * 4;
    const int xx = idx / C;                // pixel within quad
    const int c  = idx % C;                // 4 consecutive channels
    const int x  = m * S_ + xx;
    const float vals[4] = {acc.x, acc.y, acc.z, acc.w};
    float* op = out + (size_t)c * (H * H) + (size_t)y * H + x;
#pragma unroll
    for (int e = 0; e < 4; ++e)
        op[(size_t)e * (H * H)] = vals[e] * (1.f / 9.f);
}

__global__ __launch_bounds__(256) void foldT_kernel(const float* __restrict__ T1t,
                                                    const float* __restrict__ T2t,
                                                    const float* __restrict__ T3t,
                                                    const int* __restrict__ argb,
                                                    float* __restrict__ T1,
                                                    float* __restrict__ T2,
                                                    float* __restrict__ T3) {
    const int b = blockIdx.x, w = threadIdx.x >> 6, lane = threadIdx.x & 63;
    if (b < 576)        foldT<1, 256, 48>(T3t, argb, T3, b * 4 + w, lane);
    else if (b < 1728)  foldT<2, 128, 96>(T2t, argb, T2, (b - 576) * 4 + w, lane);
    else                foldT<4, 64, 192>(T1t, argb, T1, (b - 1728) * 4 + w, lane);
}

extern "C" void kernel_launch(void* const* d_in, const int* in_sizes, int n_in,
                              void* d_out, int out_size, void* d_ws, size_t ws_size,
                              hipStream_t stream) {
    const float* lrsr  = (const float*)d_in[0];  // (1,256,48,48)
    const float* refsr = (const float*)d_in[1];  // (1,256,48,48)
    const float* ref1  = (const float*)d_in[2];  // (1,64,192,192)
    const float* ref2  = (const float*)d_in[3];  // (1,128,96,96)
    const float* ref3  = (const float*)d_in[4];  // (1,256,48,48)

    float* out = (float*)d_out;
    float* S   = out;                         // 2304
    float* T3  = S  + NPOS;                   // 256*48*48
    float* T2  = T3 + 256 * 48 * 48;          // 128*96*96
    float* T1  = T2 + 128 * 96 * 96;          // 64*192*192

    float*  P      = (float*)d_ws;                    // 2304*2500 f32 = 23.04 MB
    float*  SS2    = P + (size_t)NPOS * PCOLS;        // 2*2304
    float*  inv2   = SS2 + 2 * NPOS;                  // 2*2304 (inl, inr)
    int*    argb   = (int*)(inv2 + 2 * NPOS);         // 2304
    ushort* planes = (ushort*)(argb + NPOS);          // 6*PLANESZ bf16 = 7.08 MB
    float*  inl    = inv2;
    float*  inr    = inv2 + NPOS;

    const size_t need  = ((size_t)NPOS * PCOLS + 5 * NPOS) * 4 + (size_t)6 * PLANESZ * 2;
    const size_t nhwcB = (size_t)(2304 * 256 + 9216 * 128 + 36864 * 64) * 4;  // 16.5 MB
    const int mfma_path = ws_size >= need ? 1 : 0;
    const int bigws     = ws_size >= need + nhwcB ? 1 : 0;

    // NHWC refs: separate region if it fits, else alias dead-after-maxarg P
    float* T3t = bigws ? (float*)((char*)d_ws + need) : P;
    float* T2t = T3t + 2304 * 256;
    float* T1t = T2t + 9216 * 128;

    // K1: ss2 + split + P border zeroing (+ transpose when bigws)
    {
        const int tbase = mfma_path ? 2412 : 1836;
        const int grid  = tbase + (bigws ? 1008 : 0);
        prep_kernel<<<grid, 256, 0, stream>>>(lrsr, refsr, ref1, ref2, ref3,
                                              SS2, planes, P, T3t, T2t, T1t,
                                              mfma_path, bigws ? tbase : grid + 1);
    }

    // K2: invnorm + gemm
    if (mfma_path) {
        corr_kernel<<<18 + 1296, 256, 0, stream>>>(SS2, inv2, planes, P, 1);
    } else {
        corr_kernel<<<18, 256, 0, stream>>>(SS2, inv2, planes, P, 0);
        gemm_p_kernel<<<dim3(NPOS / TN, NPOS / TM), 256, 0, stream>>>(lrsr, refsr, P);
    }

    // K3: paired maxarg (last reader of P)
    maxarg_kernel<<<1152, 192, 0, stream>>>(P, inr, inl, S, argb);

    // fallback path: transpose into dead P region after maxarg
    if (!bigws)
        transposeT_kernel<<<1008, 256, 0, stream>>>(ref1, ref2, ref3, T3t, T2t, T1t);

    // K4: coalesced folds, plain write-back stores
    foldT_kernel<<<4032, 256, 0, stream>>>(T1t, T2t, T3t, argb, T1, T2, T3);
}

// Round 12
// 81.523 us; speedup vs baseline: 1.3644x; 1.0536x over previous
//
#include <hip/hip_runtime.h>
#include <hip/hip_bf16.h>
#include <math.h>

#define HW 48
#define NPOS 2304      // 48*48
#define CCH 256
#define PCOLS 2500     // padded 50x50 grid per P row
#define PLANESZ (NPOS * CCH)   // elements per bf16 plane
#define KC 16
#define TM 128
#define TN 64

typedef __attribute__((ext_vector_type(8))) short short8v;
typedef __attribute__((ext_vector_type(16))) float f32x16;

// ---------------- phase: per-pixel sum of squares ---------------------------
__device__ inline void ph_ss2(int vb, const float* __restrict__ lr,
                              const float* __restrict__ ref, float* __restrict__ SS2,
                              float (*red)[64]) {
    const int img = vb / 36, bx = vb % 36;
    const float* imgp = img ? ref : lr;
    const int t = threadIdx.x;
    const int px = t & 63, cg = t >> 6;
    const int p = bx * 64 + px;
    const float* base = imgp + (size_t)cg * 64 * NPOS + p;
    float s = 0.f;
#pragma unroll 4
    for (int cc = 0; cc < 64; ++cc) {
        float v = base[(size_t)cc * NPOS];
        s = fmaf(v, v, s);
    }
    red[cg][px] = s;
    __syncthreads();
    if (cg == 0)
        SS2[img * NPOS + p] = red[0][px] + red[1][px] + red[2][px] + red[3][px];
}

// ---------------- phase: f32 -> 3-term bf16 split, fragment layout ----------
__device__ inline void ph_split(int local, const float* __restrict__ lr,
                                const float* __restrict__ ref, ushort* __restrict__ planes) {
    const int img = local / 288;
    const int gid = (local % 288) * 256 + threadIdx.x;   // octet id, 73728 per image
    const float* src = img ? ref : lr;
    const int lane = gid & 63;
    const int k16  = (gid >> 6) & 15;
    const int blk  = gid >> 10;
    const int pos  = blk * 32 + (lane & 31);
    const int c0   = k16 * 16 + (lane >> 5) * 8;
    ushort h8[8], m8[8], l8[8];
#pragma unroll
    for (int e = 0; e < 8; ++e) {
        float a = src[(size_t)(c0 + e) * NPOS + pos];
        __hip_bfloat16 hb = __float2bfloat16(a);
        float hf = __bfloat162float(hb);
        float r1 = a - hf;
        __hip_bfloat16 mb = __float2bfloat16(r1);
        float mf = __bfloat162float(mb);
        __hip_bfloat16 lb = __float2bfloat16(r1 - mf);
        h8[e] = *(ushort*)&hb;
        m8[e] = *(ushort*)&mb;
        l8[e] = *(ushort*)&lb;
    }
    ushort* ph = planes + (size_t)(img * 3 + 0) * PLANESZ + (size_t)gid * 8;
    ushort* pm = planes + (size_t)(img * 3 + 1) * PLANESZ + (size_t)gid * 8;
    ushort* pl = planes + (size_t)(img * 3 + 2) * PLANESZ + (size_t)gid * 8;
#pragma unroll
    for (int e = 0; e < 8; ++e) { ph[e] = h8[e]; pm[e] = m8[e]; pl[e] = l8[e]; }
}

// ---------------- phase: zero padded-border cells of P ----------------------
__device__ inline void ph_zero(int local, float* __restrict__ P) {
    const int idx = local * 256 + threadIdx.x;
    if (idx >= NPOS * 196) return;
    const int row = idx / 196, b = idx - row * 196;
    int pc;
    if (b < 50)       pc = b;
    else if (b < 100) pc = 2450 + (b - 50);
    else {
        const int i = b - 100;
        const int rr = 1 + (i >> 1);
        pc = rr * 50 + ((i & 1) ? 49 : 0);
    }
    P[(size_t)row * PCOLS + pc] = 0.f;
}

// ---------------- phase: NCHW -> NHWC transpose (1008 vblocks) --------------
__device__ inline void ph_transpose(int b, const float* __restrict__ ref1,
                                    const float* __restrict__ ref2,
                                    const float* __restrict__ ref3,
                                    float* __restrict__ T3t, float* __restrict__ T2t,
                                    float* __restrict__ T1t, float (*tile)[65]) {
    const float* src; float* dst; int C, NPIX, tpx, tch;
    if (b < 144)      { src = ref3; dst = T3t; C = 256; NPIX = 2304;  tpx = b % 36;  tch = b / 36; }
    else if (b < 432) { const int lb = b - 144; src = ref2; dst = T2t; C = 128; NPIX = 9216;  tpx = lb % 144; tch = lb / 144; }
    else              { const int lb = b - 432; src = ref1; dst = T1t; C = 64;  NPIX = 36864; tpx = lb;       tch = 0; }
    const int t = threadIdx.x;
    const int px0 = tpx * 64, c0 = tch * 64;
#pragma unroll
    for (int r = 0; r < 16; ++r) {
        const int cl = r * 4 + (t >> 6), pl = t & 63;
        tile[cl][pl] = src[(size_t)(c0 + cl) * NPIX + px0 + pl];
    }
    __syncthreads();
#pragma unroll
    for (int r = 0; r < 16; ++r) {
        const int pl = r * 4 + (t >> 6), cl = t & 63;
        dst[(size_t)(px0 + pl) * C + c0 + cl] = tile[cl][pl];
    }
}

// ---------------- K1: ss2 | split | zero-border | (transpose if bigws) ------
__global__ __launch_bounds__(256) void prep_kernel(const float* __restrict__ lr,
                                                   const float* __restrict__ ref,
                                                   const float* __restrict__ ref1,
                                                   const float* __restrict__ ref2,
                                                   const float* __restrict__ ref3,
                                                   float* __restrict__ SS2,
                                                   ushort* __restrict__ planes,
                                                   float* __restrict__ P,
                                                   float* __restrict__ T3t,
                                                   float* __restrict__ T2t,
                                                   float* __restrict__ T1t,
                                                   int do_split, int tbase) {
    __shared__ union {
        float red[4][64];
        float tile[64][65];
    } sm;
    const int b = blockIdx.x;
    if (b >= tbase) {
        ph_transpose(b - tbase, ref1, ref2, ref3, T3t, T2t, T1t, sm.tile);
        return;
    }
    if (do_split) {
        if (b < 72)        ph_ss2(b, lr, ref, SS2, sm.red);
        else if (b < 648)  ph_split(b - 72, lr, ref, planes);
        else               ph_zero(b - 648, P);
    } else {
        if (b < 72)        ph_ss2(b, lr, ref, SS2, sm.red);
        else               ph_zero(b - 72, P);
    }
}

// ---------------- standalone transpose (fallback path, aliases dead P) ------
__global__ __launch_bounds__(256) void transposeT_kernel(const float* __restrict__ ref1,
                                                         const float* __restrict__ ref2,
                                                         const float* __restrict__ ref3,
                                                         float* __restrict__ T3t,
                                                         float* __restrict__ T2t,
                                                         float* __restrict__ T1t) {
    __shared__ float tile[64][65];
    ph_transpose(blockIdx.x, ref1, ref2, ref3, T3t, T2t, T1t, tile);
}

// ---------------- phase: 3x3 stencil -> 1/max(norm,eps) ---------------------
__device__ inline void ph_invnorm(int vb, const float* __restrict__ SS2,
                                  float* __restrict__ inv2) {
    const int img = vb / 9;
    const int p = (vb % 9) * 256 + threadIdx.x;
    const float* SS = SS2 + img * NPOS;
    const int y = p / HW, x = p % HW;
    float s = 0.f;
#pragma unroll
    for (int di = -1; di <= 1; ++di) {
        int yy = y + di;
        if ((unsigned)yy >= HW) continue;
#pragma unroll
        for (int dj = -1; dj <= 1; ++dj) {
            int xx = x + dj;
            if ((unsigned)xx >= HW) continue;
            s += SS[yy * HW + xx];
        }
    }
    inv2[img * NPOS + p] = 1.f / fmaxf(sqrtf(s), 1e-12f);
}

// ---------------- phase: MFMA correlation GEMM (3-term split) ---------------
__device__ inline void ph_gemm(int g, const ushort* __restrict__ planes,
                               float* __restrict__ P) {
    const int bxg = g % 72, byg = g / 72;
    const int t = threadIdx.x, lane = t & 63, w = t >> 6;
    const int nblk0 = bxg;
    const int ablk  = byg * 4 + w;

    const ushort* baseA  = planes + ((size_t)(ablk * 16) * 64 + lane) * 8;
    const ushort* baseB0 = planes + (size_t)3 * PLANESZ + ((size_t)(nblk0 * 16) * 64 + lane) * 8;

    f32x16 acc0 = {};
#pragma unroll 4
    for (int k = 0; k < 16; ++k) {
        const int fo = k * 512;
        short8v ah = *(const short8v*)(baseA + fo);
        short8v am = *(const short8v*)(baseA + PLANESZ + fo);
        short8v al = *(const short8v*)(baseA + 2 * PLANESZ + fo);
        short8v bh0 = *(const short8v*)(baseB0 + fo);
        short8v bm0 = *(const short8v*)(baseB0 + PLANESZ + fo);
        short8v bl0 = *(const short8v*)(baseB0 + 2 * PLANESZ + fo);
        acc0 = __builtin_amdgcn_mfma_f32_32x32x16_bf16(ah, bh0, acc0, 0, 0, 0);
        acc0 = __builtin_amdgcn_mfma_f32_32x32x16_bf16(ah, bm0, acc0, 0, 0, 0);
        acc0 = __builtin_amdgcn_mfma_f32_32x32x16_bf16(am, bh0, acc0, 0, 0, 0);
        acc0 = __builtin_amdgcn_mfma_f32_32x32x16_bf16(ah, bl0, acc0, 0, 0, 0);
        acc0 = __builtin_amdgcn_mfma_f32_32x32x16_bf16(al, bh0, acc0, 0, 0, 0);
        acc0 = __builtin_amdgcn_mfma_f32_32x32x16_bf16(am, bm0, acc0, 0, 0, 0);
    }
    const int m0 = byg * 128 + w * 32;
    const int half = lane >> 5;
    const int colA = nblk0 * 32 + (lane & 31);
    const int pcA = (colA / 48) * 50 + colA % 48 + 51;
#pragma unroll
    for (int r = 0; r < 16; ++r) {
        const int row = (r & 3) + 8 * (r >> 2) + 4 * half;
        P[(size_t)(m0 + row) * PCOLS + pcA] = acc0[r];
    }
}

// ---------------- K2: invnorm (18 blocks) | gemm (1296 blocks) --------------
__global__ __launch_bounds__(256) void corr_kernel(const float* __restrict__ SS2,
                                                   float* __restrict__ inv2,
                                                   const ushort* __restrict__ planes,
                                                   float* __restrict__ P,
                                                   int do_gemm) {
    const int b = blockIdx.x;
    if (b < 18)          ph_invnorm(b, SS2, inv2);
    else if (do_gemm)    ph_gemm(b - 18, planes, P);
}

// ---------------- f32 fallback GEMM (if workspace too small) ----------------
__global__ __launch_bounds__(256) void gemm_p_kernel(const float* __restrict__ lr,
                                                     const float* __restrict__ ref,
                                                     float* __restrict__ P) {
    __shared__ float As[KC][TM];
    __shared__ float Bs[KC][TN];
    const int t  = threadIdx.x;
    const int tx = t & 15, ty = t >> 4;
    const int lp0 = blockIdx.y * TM, rp0 = blockIdx.x * TN;
    const int ac0 = t >> 5,        acol0 = (t & 31) << 2;
    const int ac1 = (t + 256) >> 5, acol1 = acol0;
    const int bc = t >> 4, bcol = (t & 15) << 2;
    float acc[8][4] = {};
    for (int c0 = 0; c0 < CCH; c0 += KC) {
        float4 a0 = *(const float4*)(lr  + (size_t)(c0 + ac0) * NPOS + lp0 + acol0);
        float4 a1 = *(const float4*)(lr  + (size_t)(c0 + ac1) * NPOS + lp0 + acol1);
        float4 b0 = *(const float4*)(ref + (size_t)(c0 + bc)  * NPOS + rp0 + bcol);
        __syncthreads();
        *(float4*)&As[ac0][acol0] = a0;
        *(float4*)&As[ac1][acol1] = a1;
        *(float4*)&Bs[bc][bcol]   = b0;
        __syncthreads();
#pragma unroll
        for (int kk = 0; kk < KC; ++kk) {
            float4 aA = *(const float4*)&As[kk][ty * 8];
            float4 aB = *(const float4*)&As[kk][ty * 8 + 4];
            float4 bb = *(const float4*)&Bs[kk][tx * 4];
            const float av[8] = {aA.x, aA.y, aA.z, aA.w, aB.x, aB.y, aB.z, aB.w};
            const float bv[4] = {bb.x, bb.y, bb.z, bb.w};
#pragma unroll
            for (int i = 0; i < 8; ++i)
#pragma unroll
                for (int j = 0; j < 4; ++j)
                    acc[i][j] = fmaf(av[i], bv[j], acc[i][j]);
        }
    }
    const int col0 = rp0 + tx * 4;
    const int pc0  = (col0 / 48) * 50 + (col0 % 48) + 51;
#pragma unroll
    for (int i = 0; i < 8; ++i) {
        const int m = lp0 + ty * 8 + i;
        float4 v = make_float4(acc[i][0], acc[i][1], acc[i][2], acc[i][3]);
        __builtin_memcpy(P + (size_t)m * PCOLS + pc0, &v, 16);
    }
}

// ---------------- K3: fused R-reconstruction + max/argmax -------------------
// l index XCD-swizzled: 288 consecutive l per XCD for L2 row reuse.
__global__ __launch_bounds__(192) void maxarg_kernel(const float* __restrict__ P,
                                                     const float* __restrict__ inr,
                                                     const float* __restrict__ inl,
                                                     float* __restrict__ S,
                                                     int* __restrict__ arg) {
    const int bid = blockIdx.x;
    const int l   = (bid & 7) * 288 + (bid >> 3);   // bijective, 2304 = 8*288
    const int yl = l / HW, xl = l % HW;
    const int t  = threadIdx.x;

    bool vmask[9];
    const float* bp[9];
#pragma unroll
    for (int d = 0; d < 9; ++d) {
        const int di = d / 3 - 1, dj = d % 3 - 1;
        vmask[d] = ((unsigned)(yl + di) < HW) && ((unsigned)(xl + dj) < HW);
        bp[d] = P + (ptrdiff_t)(l + di * HW + dj) * PCOLS + (di * 50 + dj);
    }

    float best = -1e30f;
    int bestr = 0;
#pragma unroll
    for (int vv = 0; vv < 3; ++vv) {
        const int v   = t + vv * 192;          // vec id 0..575
        const int yr  = v / 12;
        const int xr4 = (v - yr * 12) << 2;
        const int q0  = yr * 50 + xr4 + 51;
        const int r0  = yr * HW + xr4;
        float4 a = make_float4(0.f, 0.f, 0.f, 0.f);
#pragma unroll
        for (int d = 0; d < 9; ++d) {
            if (vmask[d]) {
                float4 x;
                __builtin_memcpy(&x, bp[d] + q0, 16);
                a.x += x.x; a.y += x.y; a.z += x.z; a.w += x.w;
            }
        }
        const float4 w = *(const float4*)(inr + r0);
        const float vals[4] = {a.x * w.x, a.y * w.y, a.z * w.z, a.w * w.w};
#pragma unroll
        for (int k = 0; k < 4; ++k)
            if (vals[k] > best) { best = vals[k]; bestr = r0 + k; }
    }

    __shared__ float bv[256];
    __shared__ int   br[256];
    bv[t] = best; br[t] = bestr;
    if (t < 64) { bv[192 + t] = -1e30f; br[192 + t] = 0; }
    __syncthreads();
    for (int s2 = 128; s2 > 0; s2 >>= 1) {
        if (t < s2) {
            float v2 = bv[t + s2]; int r2 = br[t + s2];
            if (v2 > bv[t] || (v2 == bv[t] && r2 < br[t])) { bv[t] = v2; br[t] = r2; }
        }
        __syncthreads();
    }
    if (t == 0) {
        S[l]   = bv[0] * inl[l];
        arg[l] = br[0];
    }
}

// ---------------- K4: fold from NHWC refs, coalesced 1KB gathers ------------
// Stores: plain per-lane dword scatter -- write-back L2 coalesces them
// (round-10 lesson: NT stores = 3.6x HBM write amplification; round-8:
// LDS staging of these stores also a net loss).
template <int S_, int C, int H>
__device__ inline void foldT(const float* __restrict__ refT, const int* __restrict__ arg,
                             float* __restrict__ out, int u, int lane) {
    const int y = u / 48, m = u % 48;
    const int ty_ = y / S_ + 1;            // (y+PAD)/S_, PAD==S_
    float4 acc = make_float4(0.f, 0.f, 0.f, 0.f);
#pragma unroll
    for (int a = 0; a < 3; ++a) {
        const int oy = ty_ - a;
        if ((unsigned)oy >= HW) continue;
        const int di = y + S_ - S_ * oy;   // in [0, 3S)
#pragma unroll
        for (int b = 0; b < 3; ++b) {
            const int ox = m + 1 - b;
            if ((unsigned)ox >= HW) continue;
            const int ar = arg[oy * HW + ox];
            const int ry = ar / HW, rx = ar % HW;
            const int yy  = S_ * ry + di - S_;
            const int xx0 = S_ * (rx + b - 1);
            if ((unsigned)yy < H && (unsigned)xx0 < H) {
                float4 v;
                __builtin_memcpy(&v, refT + ((size_t)yy * H + xx0) * C + lane * 4, 16);
                acc.x += v.x; acc.y += v.y; acc.z += v.z; acc.w += v.w;
            }
        }
    }
    const int idx = lane * 4;
    const int xx = idx / C;                // pixel within quad
    const int c  = idx % C;                // 4 consecutive channels
    const int x  = m * S_ + xx;
    const float vals[4] = {acc.x, acc.y, acc.z, acc.w};
    float* op = out + (size_t)c * (H * H) + (size_t)y * H + x;
#pragma unroll
    for (int e = 0; e < 4; ++e)
        op[(size_t)e * (H * H)] = vals[e] * (1.f / 9.f);
}

__global__ __launch_bounds__(256) void foldT_kernel(const float* __restrict__ T1t,
                                                    const float* __restrict__ T2t,
                                                    const float* __restrict__ T3t,
                                                    const int* __restrict__ argb,
                                                    float* __restrict__ T1,
                                                    float* __restrict__ T2,
                                                    float* __restrict__ T3) {
    const int b = blockIdx.x, w = threadIdx.x >> 6, lane = threadIdx.x & 63;
    if (b < 576)        foldT<1, 256, 48>(T3t, argb, T3, b * 4 + w, lane);
    else if (b < 1728)  foldT<2, 128, 96>(T2t, argb, T2, (b - 576) * 4 + w, lane);
    else                foldT<4, 64, 192>(T1t, argb, T1, (b - 1728) * 4 + w, lane);
}

extern "C" void kernel_launch(void* const* d_in, const int* in_sizes, int n_in,
                              void* d_out, int out_size, void* d_ws, size_t ws_size,
                              hipStream_t stream) {
    const float* lrsr  = (const float*)d_in[0];  // (1,256,48,48)
    const float* refsr = (const float*)d_in[1];  // (1,256,48,48)
    const float* ref1  = (const float*)d_in[2];  // (1,64,192,192)
    const float* ref2  = (const float*)d_in[3];  // (1,128,96,96)
    const float* ref3  = (const float*)d_in[4];  // (1,256,48,48)

    float* out = (float*)d_out;
    float* S   = out;                         // 2304
    float* T3  = S  + NPOS;                   // 256*48*48
    float* T2  = T3 + 256 * 48 * 48;          // 128*96*96
    float* T1  = T2 + 128 * 96 * 96;          // 64*192*192

    float*  P      = (float*)d_ws;                    // 2304*2500 f32 = 23.04 MB
    float*  SS2    = P + (size_t)NPOS * PCOLS;        // 2*2304
    float*  inv2   = SS2 + 2 * NPOS;                  // 2*2304 (inl, inr)
    int*    argb   = (int*)(inv2 + 2 * NPOS);         // 2304
    ushort* planes = (ushort*)(argb + NPOS);          // 6*PLANESZ bf16 = 7.08 MB
    float*  inl    = inv2;
    float*  inr    = inv2 + NPOS;

    const size_t need  = ((size_t)NPOS * PCOLS + 5 * NPOS) * 4 + (size_t)6 * PLANESZ * 2;
    const size_t nhwcB = (size_t)(2304 * 256 + 9216 * 128 + 36864 * 64) * 4;  // 16.5 MB
    const int mfma_path = ws_size >= need ? 1 : 0;
    const int bigws     = ws_size >= need + nhwcB ? 1 : 0;

    // NHWC refs: separate region if it fits, else alias dead-after-maxarg P
    float* T3t = bigws ? (float*)((char*)d_ws + need) : P;
    float* T2t = T3t + 2304 * 256;
    float* T1t = T2t + 9216 * 128;

    // K1: ss2 + split + P border zeroing (+ transpose when bigws)
    {
        const int tbase = mfma_path ? 2412 : 1836;
        const int grid  = tbase + (bigws ? 1008 : 0);
        prep_kernel<<<grid, 256, 0, stream>>>(lrsr, refsr, ref1, ref2, ref3,
                                              SS2, planes, P, T3t, T2t, T1t,
                                              mfma_path, bigws ? tbase : grid + 1);
    }

    // K2: invnorm + gemm
    if (mfma_path) {
        corr_kernel<<<18 + 1296, 256, 0, stream>>>(SS2, inv2, planes, P, 1);
    } else {
        corr_kernel<<<18, 256, 0, stream>>>(SS2, inv2, planes, P, 0);
        gemm_p_kernel<<<dim3(NPOS / TN, NPOS / TM), 256, 0, stream>>>(lrsr, refsr, P);
    }

    // K3: maxarg (last reader of P)
    maxarg_kernel<<<NPOS, 192, 0, stream>>>(P, inr, inl, S, argb);

    // fallback path: transpose into dead P region after maxarg
    if (!bigws)
        transposeT_kernel<<<1008, 256, 0, stream>>>(ref1, ref2, ref3, T3t, T2t, T1t);

    // K4: coalesced folds, plain write-back stores
    foldT_kernel<<<4032, 256, 0, stream>>>(T1t, T2t, T3t, argb, T1, T2, T3);
}